// Round 1
// baseline (829.017 us; speedup 1.0000x reference)
//
#include <hip/hip_runtime.h>
#include <math.h>

// Problem constants (fixed by setup_inputs): B=128, R=4096, D=256, fp32.
constexpr int R = 4096;
constexpr int D = 256;

__device__ __forceinline__ float wave_sum(float v) {
    #pragma unroll
    for (int o = 32; o >= 1; o >>= 1) v += __shfl_xor(v, o, 64);
    return v;
}

// ---------------------------------------------------------------------------
// Kernel 1: per-sample normalize q. grid=B, block=256 (one thread per dim).
// ---------------------------------------------------------------------------
__global__ void knorm_q(const float* __restrict__ reps, const int* __restrict__ qrels,
                        float* __restrict__ qn) {
    int b = blockIdx.x;
    int qidx = qrels[b];
    const float* q = reps + ((size_t)b * R + (size_t)qidx) * D;
    int d = threadIdx.x;
    float v = q[d];
    float ss = wave_sum(v * v);
    __shared__ float red[4];
    int wave = threadIdx.x >> 6, lane = threadIdx.x & 63;
    if (lane == 0) red[wave] = ss;
    __syncthreads();
    float tot = red[0] + red[1] + red[2] + red[3];
    float nrm = fmaxf(sqrtf(tot), 1e-12f);
    qn[(size_t)b * D + d] = v / nrm;
}

// ---------------------------------------------------------------------------
// Kernel 2: fused copy + sims. One wave per row (64 lanes x float4 = 256 f32).
// block=256 (4 waves -> 4 rows), grid = B*R/4. The HBM roofline kernel.
// ---------------------------------------------------------------------------
__global__ void kcopy_sims(const float* __restrict__ reps, const float* __restrict__ qn,
                           float* __restrict__ out, float* __restrict__ sims) {
    size_t row = (size_t)blockIdx.x * 4 + (threadIdx.x >> 6);
    int lane = threadIdx.x & 63;
    int b = (int)(row >> 12);           // R = 4096
    const float4* src = (const float4*)(reps + row * D);
    float4 v = src[lane];
    ((float4*)(out + row * D))[lane] = v;
    float4 qv = ((const float4*)(qn + (size_t)b * D))[lane];
    float dot = v.x * qv.x + v.y * qv.y + v.z * qv.z + v.w * qv.w;
    float nrm = v.x * v.x + v.y * v.y + v.z * v.z + v.w * v.w;
    #pragma unroll
    for (int o = 32; o >= 1; o >>= 1) {
        dot += __shfl_xor(dot, o, 64);
        nrm += __shfl_xor(nrm, o, 64);
    }
    if (lane == 0) sims[row] = dot / fmaxf(sqrtf(nrm), 1e-12f);
}

// ---------------------------------------------------------------------------
// Kernel 3: per-sample masked-softmax coefficients. grid=B, block=256.
// sims row (16KB) staged in LDS; three sweeps: (max,count) -> (S,T) -> write.
// adjusted[r] = e*g / (T + 1e-8*S)  [softmax denom cancels analytically].
// ---------------------------------------------------------------------------
__global__ void kadjust(float* __restrict__ sims, const int* __restrict__ qrels,
                        const float* __restrict__ thrp, const float* __restrict__ wsp,
                        const float* __restrict__ tempp, int* __restrict__ cnt) {
    __shared__ float s[R];
    __shared__ float redM[4]; __shared__ int redC[4];
    __shared__ float redS[4], redT[4];
    int b = blockIdx.x;
    int qidx = qrels[b];
    float* srow = sims + (size_t)b * R;
    for (int i = threadIdx.x; i < R; i += 256) s[i] = srow[i];
    __syncthreads();
    if (threadIdx.x == 0) s[qidx] = -1.0f;   // exclude self
    __syncthreads();

    float threshold = 1.f / (1.f + expf(-thrp[0]));
    float temp = fminf(fmaxf(tempp[0], 0.1f), 10.f);
    float wscale = wsp[0];
    int wave = threadIdx.x >> 6, lane = threadIdx.x & 63;

    // sweep A: M = max(logits), c = #valid.  (-1e9 floor matches reference.)
    float M = -1e9f; int c = 0;
    for (int i = threadIdx.x; i < R; i += 256) {
        float sv = s[i];
        if (sv > threshold) { M = fmaxf(M, sv / temp); c++; }
    }
    #pragma unroll
    for (int o = 32; o >= 1; o >>= 1) {
        M = fmaxf(M, __shfl_xor(M, o, 64));
        c += __shfl_xor(c, o, 64);
    }
    if (lane == 0) { redM[wave] = M; redC[wave] = c; }
    __syncthreads();
    M = fmaxf(fmaxf(redM[0], redM[1]), fmaxf(redM[2], redM[3]));
    c = redC[0] + redC[1] + redC[2] + redC[3];

    // sweep B: S = sum e, T = sum e*g
    float S = 0.f, T = 0.f;
    for (int i = threadIdx.x; i < R; i += 256) {
        float sv = s[i];
        bool m = sv > threshold;
        float logit = m ? sv / temp : -1e9f;
        float e = expf(logit - M);            // underflows to 0 for masked-out
        float g = 0.f;
        if (m) {
            float simw = 1.f / (1.f + expf(-(sv - threshold) * 10.f));
            g = simw * (1.f + wscale * sv);
        }
        S += e; T += e * g;
    }
    S = wave_sum(S); T = wave_sum(T);
    if (lane == 0) { redS[wave] = S; redT[wave] = T; }
    __syncthreads();
    S = redS[0] + redS[1] + redS[2] + redS[3];
    T = redT[0] + redT[1] + redT[2] + redT[3];
    float denom = T + 1e-8f * S;

    // sweep C: write adjusted coefficients (in place over sims)
    for (int i = threadIdx.x; i < R; i += 256) {
        float sv = s[i];
        bool m = sv > threshold;
        float a = 0.f;
        if (m) {
            float e = expf(sv / temp - M);
            float simw = 1.f / (1.f + expf(-(sv - threshold) * 10.f));
            a = e * simw * (1.f + wscale * sv) / denom;
        }
        srow[i] = a;
    }
    if (threadIdx.x == 0) cnt[b] = c;
}

// ---------------------------------------------------------------------------
// Kernel 4: weighted sum + write new query row. grid=B, block=256 (thread=dim).
// Skips entirely when no valid neighbors (out row already == q from the copy).
// Coefficient chunks staged in LDS; zero coefficients skip the row read.
// ---------------------------------------------------------------------------
__global__ void kfinal(const float* __restrict__ reps, const float* __restrict__ adj,
                       const int* __restrict__ qrels, const int* __restrict__ cnt,
                       const float* __restrict__ strp, float* __restrict__ out) {
    int b = blockIdx.x;
    if (cnt[b] == 0) return;                 // block-uniform
    int qidx = qrels[b];
    int d = threadIdx.x;
    __shared__ float a_sh[256];
    float acc = 0.f;
    const float* rb = reps + (size_t)b * R * D;
    const float* ab = adj + (size_t)b * R;
    for (int chunk = 0; chunk < R; chunk += 256) {
        __syncthreads();
        a_sh[threadIdx.x] = ab[chunk + threadIdx.x];
        __syncthreads();
        for (int j = 0; j < 256; j++) {
            float a = a_sh[j];                // block-uniform branch
            if (a != 0.f) acc += a * rb[(size_t)(chunk + j) * D + d];
        }
    }
    float strength = (1.f / (1.f + expf(-strp[0]))) * 0.2f;
    float qd = rb[(size_t)qidx * D + d];
    out[((size_t)b * R + (size_t)qidx) * D + d] = (1.f - strength) * qd + strength * acc;
}

// ---------------------------------------------------------------------------
extern "C" void kernel_launch(void* const* d_in, const int* in_sizes, int n_in,
                              void* d_out, int out_size, void* d_ws, size_t ws_size,
                              hipStream_t stream) {
    const float* reps  = (const float*)d_in[0];
    const int*   qrels = (const int*)d_in[1];
    const float* thrp  = (const float*)d_in[2];
    const float* strp  = (const float*)d_in[3];
    const float* wsp   = (const float*)d_in[4];
    const float* tempp = (const float*)d_in[5];
    float* out = (float*)d_out;
    int B = in_sizes[1];

    // workspace layout: qn [B*D] | sims/adjusted [B*R] | cnt [B]   (~2.2 MB)
    float* qn   = (float*)d_ws;
    float* sims = qn + (size_t)B * D;
    int*   cnt  = (int*)(sims + (size_t)B * R);

    knorm_q   <<<B,              256, 0, stream>>>(reps, qrels, qn);
    kcopy_sims<<<(B * R) / 4,    256, 0, stream>>>(reps, qn, out, sims);
    kadjust   <<<B,              256, 0, stream>>>(sims, qrels, thrp, wsp, tempp, cnt);
    kfinal    <<<B,              256, 0, stream>>>(reps, sims, qrels, cnt, strp, out);
}